// Round 1
// baseline (263.344 us; speedup 1.0000x reference)
//
#include <hip/hip_runtime.h>

// out[b,s,d] = alpha * sum_{j=1..P} beta^{j-1} x[b,s-j,d] + pf[d] + pb[((s>>5)-d)&31]
// Sliding-window recurrence: y(t+1) = beta*y(t) + alpha*x[t] - alpha*beta^P*x[t-P]

constexpr int S     = 1024;
constexpr int D     = 32;
constexpr int L     = 512;          // outputs per block (s-extent)
constexpr int HALO  = 128;          // = past_steps
constexpr int TROWS = L + HALO;     // 640 rows staged
constexpr int CHAIN = 64;           // serial outputs per thread
constexpr int NTHR  = D * (L / CHAIN); // 256 threads

__global__ __launch_bounds__(NTHR)
void attn_pred_kernel(const float* __restrict__ x,
                      const float* __restrict__ alpha_p,
                      const float* __restrict__ beta_p,
                      const float* __restrict__ pos_fwd,
                      const float* __restrict__ pos_bwd,
                      const int*   __restrict__ past_p,
                      float* __restrict__ out)
{
    __shared__ float xs[TROWS * D];  // 80 KiB -> 2 blocks/CU

    const int tid = threadIdx.x;
    const int b   = blockIdx.x >> 1;
    const int s0  = (blockIdx.x & 1) * L;

    const float alpha = alpha_p[0];
    const float beta  = beta_p[0];
    const int   P     = past_p[0];   // 128

    // alpha * beta^P, accumulated in double to avoid pow-chain drift
    double bp = 1.0;
    for (int i = 0; i < P; ++i) bp *= (double)beta;
    const float abP = alpha * (float)bp;

    // ---- stage x[b, s0-HALO : s0+L, :] into LDS (zero-fill s < 0) ----
    const float4* xg  = reinterpret_cast<const float4*>(x + (size_t)b * S * D);
    float4*       xs4 = reinterpret_cast<float4*>(xs);
    const int base_row = s0 - HALO;
    #pragma unroll
    for (int k = tid; k < TROWS * (D / 4); k += NTHR) {   // 20 iters, coalesced 16B/lane
        const int r = k >> 3;                 // tile row
        const int s = base_row + r;           // global s
        float4 v = make_float4(0.f, 0.f, 0.f, 0.f);
        if (s >= 0) v = xg[(size_t)s * (D / 4) + (k & 7)];
        xs4[k] = v;
    }
    __syncthreads();

    const int d      = tid & (D - 1);
    const int chunk  = tid >> 5;              // 0..7
    const int sstart = s0 + chunk * CHAIN;    // first output s of this thread
    const int rstart = HALO + chunk * CHAIN;  // its tile row

    const float pfv = pos_fwd[d];
    const float pbv = pos_bwd[d];             // lane l holds pos_bwd[l & 31]

    // ---- prime: y(sstart) = alpha * sum_{j=1..P} beta^{j-1} x[sstart-j] ----
    // Horner ascending over u = sstart-P .. sstart-1 (rows rstart-P .. rstart-1)
    float yhat = 0.f;
    const int r0 = rstart - P;                // = chunk*CHAIN >= 0
    #pragma unroll 16
    for (int j = 0; j < P; ++j)
        yhat = yhat * beta + xs[(r0 + j) * D + d];
    float y = alpha * yhat;

    // ---- main chain: write y(t), then advance the window ----
    float* og = out + ((size_t)b * S + sstart) * D + d;
    #pragma unroll
    for (int h = 0; h < CHAIN / 32; ++h) {
        // t>>5 is constant over each 32-run (sstart is a multiple of 64)
        const int q = (sstart >> 5) + h;
        const float pbc = __shfl(pbv, (q - d) & (D - 1), 64);
        #pragma unroll 8
        for (int i2 = 0; i2 < 32; ++i2) {
            const int i   = h * 32 + i2;
            og[i * D] = y + pfv + pbc;
            const int row = rstart + i;
            const float xt = xs[row * D + d];
            const float xl = xs[(row - P) * D + d];
            y = beta * y + alpha * xt - abP * xl;
        }
    }
}

extern "C" void kernel_launch(void* const* d_in, const int* in_sizes, int n_in,
                              void* d_out, int out_size, void* d_ws, size_t ws_size,
                              hipStream_t stream) {
    const float* x  = (const float*)d_in[0];
    const float* al = (const float*)d_in[1];
    const float* be = (const float*)d_in[2];
    const float* pf = (const float*)d_in[3];
    const float* pb = (const float*)d_in[4];
    const int*   ps = (const int*)d_in[5];
    float* out = (float*)d_out;

    const int B = in_sizes[0] / (S * D);      // 1024
    dim3 grid(B * (S / L));                   // 2048 blocks
    attn_pred_kernel<<<grid, NTHR, 0, stream>>>(x, al, be, pf, pb, ps, out);
}